// Round 5
// baseline (940.819 us; speedup 1.0000x reference)
//
#include <hip/hip_runtime.h>
#include <math.h>

#define NB 32768
#define EPS_REC 1e-4f

// Inter-stage staging (static device globals: graph-capture safe).
__device__ float g_x2[NB * 256];  // stage-1 output: B x 16 x 16
__device__ float g_x3[NB * 16];   // stage-2 output: B x 4 x 4

// Wave-synchronous "barrier": matrix groups live entirely inside one wave64,
// lanes run in lockstep, same-wave LDS ops complete in order. Only compiler
// reordering must be inhibited -> zero HW cost.
__device__ __forceinline__ void wsync() {
  asm volatile("" ::: "memory");
  __builtin_amdgcn_wave_barrier();
  asm volatile("" ::: "memory");
}

// Swap values between adjacent lanes (lane ^ 1) via DPP quad_perm [1,0,3,2].
// Pairs (2k,2k+1) are even-aligned so they never cross a quad. VALU-pipe op.
__device__ __forceinline__ float dpp_swap1(float x) {
  int xi = __builtin_bit_cast(int, x);
  int yi = __builtin_amdgcn_update_dpp(xi, xi, 0xB1, 0xF, 0xF, true);
  return __builtin_bit_cast(float, yi);
}

// Tournament (circle-method) slot permutation: content of slot s moves to
// permf(s). Over N-1 rounds with fixed pairing (2k,2k+1) every pair meets
// exactly once.
__host__ __device__ constexpr int permf(int s, int n) {
  return s == 0 ? 0
       : s == 2 ? 1
       : (s & 1) ? (s == n - 1 ? n - 2 : s + 2)
       : s - 2;
}

// Jacobi rotation (c,s) zeroing A[p][q]; G = [[c,s],[-s,c]].
__device__ __forceinline__ void rot_cs(float app, float aqq, float apq,
                                       float& c, float& s) {
  float dd = 0.5f * (app - aqq);
  float q2 = apq * apq;
  float hh = dd * dd + q2 + 1e-30f;
  float h = sqrtf(hh);
  float u = fabsf(dd) + h;
  float gi = rsqrtf(u * u + q2);
  c = u * gi;
  float smag = apq * gi;
  s = (dd >= 0.f) ? -smag : smag;
}

// One DUAL-CHAIN Jacobi round: two independent matrices (A,B) per lane-group
// for ILP (latency hiding at capped wave residency). Static slot pairing
// (2k,2k+1), data permuted by permf. A in LDS chunk-major:
// SA4[t*N + j] = rows 4t..4t+3 of column-slot j. U rows ping-pong through
// register arrays (static indices). Partner values via DPP, not LDS.
template <int N>
__device__ __forceinline__ void jround2(
    float* __restrict__ SAa, float* __restrict__ SAb, float2* __restrict__ CSa,
    float2* __restrict__ CSb, const float* __restrict__ uaA,
    float* __restrict__ ubA, const float* __restrict__ uaB,
    float* __restrict__ ubB, int sub, int kpair, float sgnS, int appAddr,
    int aqqAddr, int wcol) {
  constexpr int C = N / 4;
  float4* SA4a = (float4*)SAa;
  float4* SA4b = (float4*)SAb;
  float2 a01A = *(const float2*)(SAa + appAddr);  // app, apq (adjacent rows)
  float aqqA = SAa[aqqAddr];
  float2 a01B = *(const float2*)(SAb + appAddr);
  float aqqB = SAb[aqqAddr];
  float cA, sA, cB, sB;
  rot_cs(a01A.x, aqqA, a01A.y, cA, sA);
  rot_cs(a01B.x, aqqB, a01B.y, cB, sB);
  // both lanes of a pair write identical (c,s) to the same address
  CSa[kpair] = make_float2(cA, sA);
  CSb[kpair] = make_float2(cB, sB);
  float betaA = sgnS * sA;
  float betaB = sgnS * sB;
  wsync();
  const float4* CS4a = (const float4*)CSa;
  const float4* CS4b = (const float4*)CSb;
  float nnA[N], nnB[N];
#pragma unroll
  for (int t = 0; t < C; ++t) {
    float4 csA = CS4a[t];             // (c,s) of pairs 2t,2t+1 (broadcast)
    float4 ocA = SA4a[t * N + sub];   // own column rows 4t..4t+3, chain A
    float4 csB = CS4b[t];
    float4 ocB = SA4b[t * N + sub];
    {  // chain A, pair 2t: rows p=4t, q=4t+1
      const int p = 4 * t, q = 4 * t + 1;
      float xr = csA.x * ocA.x - csA.y * ocA.y;
      float yr = csA.y * ocA.x + csA.x * ocA.y;
      nnA[permf(p, N)] = cA * xr + betaA * dpp_swap1(xr);
      nnA[permf(q, N)] = cA * yr + betaA * dpp_swap1(yr);
      float ux = uaA[p], uy = uaA[q];
      ubA[permf(p, N)] = csA.x * ux - csA.y * uy;
      ubA[permf(q, N)] = csA.y * ux + csA.x * uy;
    }
    {  // chain A, pair 2t+1: rows p=4t+2, q=4t+3
      const int p = 4 * t + 2, q = 4 * t + 3;
      float xr = csA.z * ocA.z - csA.w * ocA.w;
      float yr = csA.w * ocA.z + csA.z * ocA.w;
      nnA[permf(p, N)] = cA * xr + betaA * dpp_swap1(xr);
      nnA[permf(q, N)] = cA * yr + betaA * dpp_swap1(yr);
      float ux = uaA[p], uy = uaA[q];
      ubA[permf(p, N)] = csA.z * ux - csA.w * uy;
      ubA[permf(q, N)] = csA.w * ux + csA.z * uy;
    }
    {  // chain B, pair 2t
      const int p = 4 * t, q = 4 * t + 1;
      float xr = csB.x * ocB.x - csB.y * ocB.y;
      float yr = csB.y * ocB.x + csB.x * ocB.y;
      nnB[permf(p, N)] = cB * xr + betaB * dpp_swap1(xr);
      nnB[permf(q, N)] = cB * yr + betaB * dpp_swap1(yr);
      float ux = uaB[p], uy = uaB[q];
      ubB[permf(p, N)] = csB.x * ux - csB.y * uy;
      ubB[permf(q, N)] = csB.y * ux + csB.x * uy;
    }
    {  // chain B, pair 2t+1
      const int p = 4 * t + 2, q = 4 * t + 3;
      float xr = csB.z * ocB.z - csB.w * ocB.w;
      float yr = csB.w * ocB.z + csB.z * ocB.w;
      nnB[permf(p, N)] = cB * xr + betaB * dpp_swap1(xr);
      nnB[permf(q, N)] = cB * yr + betaB * dpp_swap1(yr);
      float ux = uaB[p], uy = uaB[q];
      ubB[permf(p, N)] = csB.z * ux - csB.w * uy;
      ubB[permf(q, N)] = csB.w * ux + csB.z * uy;
    }
  }
  wsync();  // all reads of old columns precede any overwrite (lockstep)
#pragma unroll
  for (int t = 0; t < C; ++t) {
    SA4a[t * N + wcol] =
        make_float4(nnA[4 * t], nnA[4 * t + 1], nnA[4 * t + 2], nnA[4 * t + 3]);
    SA4b[t * N + wcol] =
        make_float4(nnB[4 * t], nnB[4 * t + 1], nnB[4 * t + 2], nnB[4 * t + 3]);
  }
  wsync();
}

// iters must be even (ping-pong); final U rows end in urA/urB.
template <int N>
__device__ __forceinline__ void jacobi2(float* SAa, float* SAb, float2* CSa,
                                        float2* CSb, float* urA, float* unA,
                                        float* urB, float* unB, int sub,
                                        int iters) {
  const int kpair = sub >> 1;
  const float sgnS = (sub & 1) ? 1.f : -1.f;  // beta = isP ? -s : s
  const int pp = sub & ~1;
  const int qq = pp + 1;
  const int appAddr = ((pp >> 2) * N + pp) * 4 + (pp & 3);
  const int aqqAddr = ((qq >> 2) * N + qq) * 4 + (qq & 3);
  const int wcol = permf(sub, N);
#pragma unroll 1
  for (int it = 0; it < iters; it += 2) {
    jround2<N>(SAa, SAb, CSa, CSb, urA, unA, urB, unB, sub, kpair, sgnS,
               appAddr, aqqAddr, wcol);
    jround2<N>(SAa, SAb, CSa, CSb, unA, urA, unB, urB, sub, kpair, sgnS,
               appAddr, aqqAddr, wcol);
  }
}

// Stage 1: X1 = w1^T X w1 (19 padded to 20), ReEig via Jacobi, then
// X2 = Y^T Lam Y with Y = U^T w2. 3 lane-groups/wave x 2 chains = 6 matrices
// per wave, 12 per 128-thread block. Lanes 60..63 -> shared dummy group 6.
__global__ __launch_bounds__(128, 2) void spd_stage1(
    const float* __restrict__ x, const float* __restrict__ w1,
    const float* __restrict__ w2) {
  __shared__ float4 SA[7 * 202];  // per group: chain A @0, chain B @101
  __shared__ float2 CS[7 * 28];   // chain A @0, chain B @14
  __shared__ float SL[7 * 44];    // chain A @0, chain B @22
  int tid = threadIdx.x;
  int wid = tid >> 6;
  int lane = tid & 63;
  int gl = lane / 20;  // 0..3 (3 = idle lanes 60..63)
  int sub = lane - gl * 20;
  bool lane_ok = (gl < 3);
  int g = lane_ok ? (wid * 3 + gl) : 6;
  int bA = blockIdx.x * 12 + g * 2;
  int bB = bA + 1;
  bool vA = lane_ok && (bA < NB);
  bool vB = lane_ok && (bB < NB);
  float* SAa = (float*)(SA + g * 202);
  float* SAb = (float*)(SA + g * 202 + 101);
  float4* SA4a = (float4*)SAa;
  float4* SA4b = (float4*)SAb;
  float2* CSa = CS + g * 28;
  float2* CSb = CS + g * 28 + 14;
  float* SLa = SL + g * 44;
  float* SLb = SL + g * 44 + 22;

  // ---- bilinear: Z = w1^T X (col sub), then X1 = Z w1, both chains ----
  float wj[19];
#pragma unroll
  for (int r = 0; r < 19; ++r) wj[r] = (sub < 19) ? w1[r * 19 + sub] : 0.f;
  {
    const float* xb = x + (vA ? bA : 0) * 361;
    float cx[19];
#pragma unroll
    for (int i = 0; i < 19; ++i) cx[i] = (sub < 19) ? xb[i * 19 + sub] : 0.f;
    float z[20];
    z[19] = 0.f;
#pragma unroll
    for (int i = 0; i < 19; ++i) {
      float acc = 0.f;
#pragma unroll
      for (int r = 0; r < 19; ++r) acc += w1[r * 19 + i] * cx[r];
      z[i] = acc;
    }
#pragma unroll
    for (int t = 0; t < 5; ++t)
      SA4a[t * 20 + sub] =
          make_float4(z[4 * t], z[4 * t + 1], z[4 * t + 2], z[4 * t + 3]);
  }
  {
    const float* xb = x + (vB ? bB : 0) * 361;
    float cx[19];
#pragma unroll
    for (int i = 0; i < 19; ++i) cx[i] = (sub < 19) ? xb[i * 19 + sub] : 0.f;
    float z[20];
    z[19] = 0.f;
#pragma unroll
    for (int i = 0; i < 19; ++i) {
      float acc = 0.f;
#pragma unroll
      for (int r = 0; r < 19; ++r) acc += w1[r * 19 + i] * cx[r];
      z[i] = acc;
    }
#pragma unroll
    for (int t = 0; t < 5; ++t)
      SA4b[t * 20 + sub] =
          make_float4(z[4 * t], z[4 * t + 1], z[4 * t + 2], z[4 * t + 3]);
  }
  wsync();
  float a1A[20], a1B[20];
#pragma unroll
  for (int i = 0; i < 20; ++i) { a1A[i] = 0.f; a1B[i] = 0.f; }
#pragma unroll
  for (int r = 0; r < 19; ++r) {
    float wr = wj[r];
#pragma unroll
    for (int t = 0; t < 5; ++t) {
      float4 za = SA4a[t * 20 + r];  // Z rows 4t..4t+3, col r (broadcast)
      a1A[4 * t + 0] += za.x * wr;
      a1A[4 * t + 1] += za.y * wr;
      a1A[4 * t + 2] += za.z * wr;
      a1A[4 * t + 3] += za.w * wr;
      float4 zb = SA4b[t * 20 + r];
      a1B[4 * t + 0] += zb.x * wr;
      a1B[4 * t + 1] += zb.y * wr;
      a1B[4 * t + 2] += zb.z * wr;
      a1B[4 * t + 3] += zb.w * wr;
    }
  }
  wsync();
  // padded A: col 19 = 0 (diag 0 -> clamped to eps; exact invariant subspace)
#pragma unroll
  for (int t = 0; t < 5; ++t) {
    SA4a[t * 20 + sub] =
        make_float4(a1A[4 * t], a1A[4 * t + 1], a1A[4 * t + 2], a1A[4 * t + 3]);
    SA4b[t * 20 + sub] =
        make_float4(a1B[4 * t], a1B[4 * t + 1], a1B[4 * t + 2], a1B[4 * t + 3]);
  }
  float urA[20], unA[20], urB[20], unB[20];
#pragma unroll
  for (int i = 0; i < 20; ++i) {
    urA[i] = (i == sub) ? 1.f : 0.f;
    urB[i] = (i == sub) ? 1.f : 0.f;
  }
  wsync();

  jacobi2<20>(SAa, SAb, CSa, CSb, urA, unA, urB, unB, sub, 96);

  const int dAddr = ((sub >> 2) * 20 + sub) * 4 + (sub & 3);
  SLa[sub] = fmaxf(SAa[dAddr], EPS_REC);
  SLb[sub] = fmaxf(SAb[dAddr], EPS_REC);
  wsync();
  // SA col sub <- U row sub  (=> SAf elem(i,j) = U[j][i])
#pragma unroll
  for (int t = 0; t < 5; ++t) {
    SA4a[t * 20 + sub] =
        make_float4(urA[4 * t], urA[4 * t + 1], urA[4 * t + 2], urA[4 * t + 3]);
    SA4b[t * 20 + sub] =
        make_float4(urB[4 * t], urB[4 * t + 1], urB[4 * t + 2], urB[4 * t + 3]);
  }
  wsync();
  // Y[r][sub] = sum_{i<19} U[i][r] * w2[i][sub]
  float wj2[19];
#pragma unroll
  for (int i = 0; i < 19; ++i) wj2[i] = (sub < 16) ? w2[i * 16 + sub] : 0.f;
  float yA[20], yB[20];
#pragma unroll
  for (int r = 0; r < 20; ++r) { yA[r] = 0.f; yB[r] = 0.f; }
#pragma unroll
  for (int i = 0; i < 19; ++i) {
    float wv = wj2[i];
#pragma unroll
    for (int t = 0; t < 5; ++t) {
      float4 ua = SA4a[t * 20 + i];  // U[i][4t..4t+3] (broadcast)
      yA[4 * t + 0] += ua.x * wv;
      yA[4 * t + 1] += ua.y * wv;
      yA[4 * t + 2] += ua.z * wv;
      yA[4 * t + 3] += ua.w * wv;
      float4 ub = SA4b[t * 20 + i];
      yB[4 * t + 0] += ub.x * wv;
      yB[4 * t + 1] += ub.y * wv;
      yB[4 * t + 2] += ub.z * wv;
      yB[4 * t + 3] += ub.w * wv;
    }
  }
  wsync();
#pragma unroll
  for (int t = 0; t < 5; ++t) {
    SA4a[t * 20 + sub] =
        make_float4(yA[4 * t], yA[4 * t + 1], yA[4 * t + 2], yA[4 * t + 3]);
    SA4b[t * 20 + sub] =
        make_float4(yB[4 * t], yB[4 * t + 1], yB[4 * t + 2], yB[4 * t + 3]);
  }
  wsync();
  float trA[20], trB[20];
#pragma unroll
  for (int r = 0; r < 20; ++r) {
    trA[r] = SLa[r] * yA[r];
    trB[r] = SLb[r] * yB[r];
  }
  if (vA && sub < 16) {
    float* outb = g_x2 + bA * 256;
#pragma unroll
    for (int i = 0; i < 16; ++i) {
      float acc = 0.f;
#pragma unroll
      for (int t = 0; t < 5; ++t) {
        float4 yc = SA4a[t * 20 + i];  // Y rows 4t..4t+3, col i (broadcast)
        acc += yc.x * trA[4 * t] + yc.y * trA[4 * t + 1] +
               yc.z * trA[4 * t + 2] + yc.w * trA[4 * t + 3];
      }
      outb[i * 16 + sub] = acc;
    }
  }
  if (vB && sub < 16) {
    float* outb = g_x2 + bB * 256;
#pragma unroll
    for (int i = 0; i < 16; ++i) {
      float acc = 0.f;
#pragma unroll
      for (int t = 0; t < 5; ++t) {
        float4 yc = SA4b[t * 20 + i];
        acc += yc.x * trB[4 * t] + yc.y * trB[4 * t + 1] +
               yc.z * trB[4 * t + 2] + yc.w * trB[4 * t + 3];
      }
      outb[i * 16 + sub] = acc;
    }
  }
}

// Stage 2: ReEig(16) via Jacobi, X3 = Y3^T Lam Y3 with Y3 = U^T w3 (16x4).
// 4 lane-groups/wave x 2 chains = 8 matrices/wave, 16 per block.
__global__ __launch_bounds__(128, 2) void spd_stage2(
    const float* __restrict__ w3) {
  __shared__ float4 SA[8 * 130];  // chain A @0, chain B @65
  __shared__ float2 CS[8 * 20];   // chain A @0, chain B @10
  __shared__ float SL[8 * 34];    // chain A @0, chain B @17
  __shared__ float4 YL[8 * 34];   // chain A @0, chain B @17
  int tid = threadIdx.x;
  int wid = tid >> 6;
  int lane = tid & 63;
  int gl = lane >> 4;
  int sub = lane & 15;
  int g = wid * 4 + gl;  // 0..7
  int bA = blockIdx.x * 16 + g * 2;
  int bB = bA + 1;
  float* SAa = (float*)(SA + g * 130);
  float* SAb = (float*)(SA + g * 130 + 65);
  float4* SA4a = (float4*)SAa;
  float4* SA4b = (float4*)SAb;
  float2* CSa = CS + g * 20;
  float2* CSb = CS + g * 20 + 10;
  float* SLa = SL + g * 34;
  float* SLb = SL + g * 34 + 17;
  float* YLa = (float*)(YL + g * 34);
  float* YLb = (float*)(YL + g * 34 + 17);

  {
    const float* xb = g_x2 + bA * 256;
    float ca[16];
#pragma unroll
    for (int i = 0; i < 16; ++i) ca[i] = xb[i * 16 + sub];
#pragma unroll
    for (int t = 0; t < 4; ++t)
      SA4a[t * 16 + sub] =
          make_float4(ca[4 * t], ca[4 * t + 1], ca[4 * t + 2], ca[4 * t + 3]);
  }
  {
    const float* xb = g_x2 + bB * 256;
    float ca[16];
#pragma unroll
    for (int i = 0; i < 16; ++i) ca[i] = xb[i * 16 + sub];
#pragma unroll
    for (int t = 0; t < 4; ++t)
      SA4b[t * 16 + sub] =
          make_float4(ca[4 * t], ca[4 * t + 1], ca[4 * t + 2], ca[4 * t + 3]);
  }
  float urA[16], unA[16], urB[16], unB[16];
#pragma unroll
  for (int i = 0; i < 16; ++i) {
    urA[i] = (i == sub) ? 1.f : 0.f;
    urB[i] = (i == sub) ? 1.f : 0.f;
  }
  wsync();

  jacobi2<16>(SAa, SAb, CSa, CSb, urA, unA, urB, unB, sub, 76);

  const int dAddr = ((sub >> 2) * 16 + sub) * 4 + (sub & 3);
  SLa[sub] = fmaxf(SAa[dAddr], EPS_REC);
  SLb[sub] = fmaxf(SAb[dAddr], EPS_REC);
  wsync();
#pragma unroll
  for (int t = 0; t < 4; ++t) {
    SA4a[t * 16 + sub] =
        make_float4(urA[4 * t], urA[4 * t + 1], urA[4 * t + 2], urA[4 * t + 3]);
    SA4b[t * 16 + sub] =
        make_float4(urB[4 * t], urB[4 * t + 1], urB[4 * t + 2], urB[4 * t + 3]);
  }
  wsync();
  // Y3[sub][j] = sum_i U[i][sub]*w3[i][j]; U[i][sub] = SAf elem(sub,i)
  float y3A[4] = {0.f, 0.f, 0.f, 0.f};
  float y3B[4] = {0.f, 0.f, 0.f, 0.f};
  const int rowBase = (sub >> 2) * 64 + (sub & 3);
#pragma unroll
  for (int i = 0; i < 16; ++i) {
    float ua = SAa[rowBase + i * 4];
    float ub = SAb[rowBase + i * 4];
#pragma unroll
    for (int j = 0; j < 4; ++j) {
      y3A[j] += ua * w3[i * 4 + j];
      y3B[j] += ub * w3[i * 4 + j];
    }
  }
  ((float4*)YLa)[sub] = make_float4(y3A[0], y3A[1], y3A[2], y3A[3]);
  ((float4*)YLb)[sub] = make_float4(y3B[0], y3B[1], y3B[2], y3B[3]);
  wsync();
  int ii = sub >> 2, jj = sub & 3;
  float accA = 0.f, accB = 0.f;
#pragma unroll
  for (int r = 0; r < 16; ++r) {
    accA += SLa[r] * YLa[r * 4 + ii] * YLa[r * 4 + jj];
    accB += SLb[r] * YLb[r * 4 + ii] * YLb[r * 4 + jj];
  }
  g_x3[bA * 16 + sub] = accA;
  g_x3[bB * 16 + sub] = accB;
}

// Stage 3: per-thread 4x4 LogEig in registers, FC(16->2), log_softmax.
__global__ __launch_bounds__(256) void spd_stage3(const float* __restrict__ fcw,
                                                  float* __restrict__ out) {
  int b = blockIdx.x * 256 + threadIdx.x;
  const float* xb = g_x3 + b * 16;
  float a[4][4];
#pragma unroll
  for (int i = 0; i < 4; ++i)
#pragma unroll
    for (int j = 0; j < 4; ++j) a[i][j] = xb[i * 4 + j];
  float vv[4][4];
#pragma unroll
  for (int i = 0; i < 4; ++i)
#pragma unroll
    for (int j = 0; j < 4; ++j) vv[i][j] = (i == j) ? 1.f : 0.f;

  constexpr int P4[6] = {0, 0, 0, 1, 1, 2};
  constexpr int Q4[6] = {1, 2, 3, 2, 3, 3};
  for (int sw = 0; sw < 6; ++sw) {
#pragma unroll
    for (int e = 0; e < 6; ++e) {
      const int p = P4[e], q = Q4[e];
      float c, s;
      rot_cs(a[p][p], a[q][q], a[p][q], c, s);
#pragma unroll
      for (int j = 0; j < 4; ++j) {
        float xx = a[p][j], yy = a[q][j];
        a[p][j] = c * xx - s * yy;
        a[q][j] = s * xx + c * yy;
      }
#pragma unroll
      for (int i = 0; i < 4; ++i) {
        float xx = a[i][p], yy = a[i][q];
        a[i][p] = c * xx - s * yy;
        a[i][q] = s * xx + c * yy;
      }
#pragma unroll
      for (int i = 0; i < 4; ++i) {
        float xx = vv[i][p], yy = vv[i][q];
        vv[i][p] = c * xx - s * yy;
        vv[i][q] = s * xx + c * yy;
      }
    }
  }
  float ll[4];
#pragma unroll
  for (int r = 0; r < 4; ++r) ll[r] = logf(fmaxf(a[r][r], 1e-12f));
  float feat[16];
#pragma unroll
  for (int i = 0; i < 4; ++i)
#pragma unroll
    for (int j = 0; j < 4; ++j) {
      float acc = 0.f;
#pragma unroll
      for (int r = 0; r < 4; ++r) acc += ll[r] * vv[i][r] * vv[j][r];
      feat[i * 4 + j] = acc;
    }
  float z0 = 0.f, z1 = 0.f;
#pragma unroll
  for (int k = 0; k < 16; ++k) {
    z0 += feat[k] * fcw[2 * k + 0];
    z1 += feat[k] * fcw[2 * k + 1];
  }
  float m = fmaxf(z0, z1);
  float lse = logf(expf(z0 - m) + expf(z1 - m));
  out[b * 2 + 0] = z0 - m - lse;
  out[b * 2 + 1] = z1 - m - lse;
#pragma unroll
  for (int k = 0; k < 16; ++k) out[2 * NB + b * 16 + k] = feat[k];
}

extern "C" void kernel_launch(void* const* d_in, const int* in_sizes, int n_in,
                              void* d_out, int out_size, void* d_ws,
                              size_t ws_size, hipStream_t stream) {
  (void)in_sizes;
  (void)n_in;
  (void)out_size;
  (void)d_ws;
  (void)ws_size;
  const float* x = (const float*)d_in[0];
  const float* w1 = (const float*)d_in[1];
  const float* w2 = (const float*)d_in[2];
  const float* w3 = (const float*)d_in[3];
  const float* fcw = (const float*)d_in[4];
  float* out = (float*)d_out;

  spd_stage1<<<(NB + 11) / 12, 128, 0, stream>>>(x, w1, w2);
  spd_stage2<<<NB / 16, 128, 0, stream>>>(w3);
  spd_stage3<<<NB / 256, 256, 0, stream>>>(fcw, out);
}